// Round 2
// baseline (369.493 us; speedup 1.0000x reference)
//
#include <hip/hip_runtime.h>

#define B_SZ   16
#define SEQ    2048
#define VOCAB  50257
#define EMBED  128
#define DSTATE 16
#define HID    256
#define NCLS   10
#define NEDGE  8192
#define KTR    64          // scan truncation: A<=0.55 -> A^64 < 2e-17
#define LN_EPS 1e-5f
#define NROW   (B_SZ*SEQ)  // 32768
#define BCAP   32          // bucket capacity per dst (Poisson lambda=4)
#define OVCAP  1024        // overflow fallback capacity

// k_prep phase block ranges
#define PB_CAST   4096                  // NROW*32/256
#define PB_BUCKET (PB_CAST + 512)       // B_SZ*NEDGE/256 = 512
#define PB_PRECM  (PB_BUCKET + 128)     // 256 hp, 2 per block
#define PB_CTAB   (PB_PRECM + 16)       // 16 d
#define PB_TOTAL  (PB_CTAB + 1)         // +1 precB

typedef float  f32x4 __attribute__((ext_vector_type(4)));
typedef short  s16x8 __attribute__((ext_vector_type(8)));

__device__ __forceinline__ float scrub(float x){
  return (x == x && fabsf(x) < 1e30f) ? x : 0.f;
}
// fp32 -> bf16 bits, round-to-nearest-even
__device__ __forceinline__ short f2b(float f){
  unsigned int u = __float_as_uint(f);
  unsigned int r = (u + 0x7fffu + ((u >> 16) & 1u)) >> 16;
  return (short)r;
}
__device__ __forceinline__ unsigned int pack2(float a, float b){
  return (unsigned int)(unsigned short)f2b(a)
       | ((unsigned int)(unsigned short)f2b(b) << 16);
}
__device__ __forceinline__ float lo2f(unsigned int v){ return __uint_as_float(v << 16); }
__device__ __forceinline__ float hi2f(unsigned int v){ return __uint_as_float(v & 0xffff0000u); }

// ---------------------------------------------------------------------------
// Heterogeneous prep kernel: all phases mutually independent. (unchanged)
__global__ __launch_bounds__(256) void k_prep(
    const int* __restrict__ tokens, const float* __restrict__ emb,
    const float* __restrict__ A_log, const float* __restrict__ B_w,
    const float* __restrict__ Wmsg, const float* __restrict__ Wupd,
    const int* __restrict__ edges,
    float* __restrict__ c_tab, short* __restrict__ Bf, float* __restrict__ MT,
    unsigned int* __restrict__ x_bf, int* __restrict__ cnt,
    unsigned short* __restrict__ bucket, int* __restrict__ ovf_cnt,
    int* __restrict__ ovf){
  int bid = blockIdx.x, tid = threadIdx.x;
  if (bid < PB_CAST){                            // ---- cast: 1,048,576 thr
    int gid = bid*256 + tid;                     // = NROW*32 exactly
    int row = gid >> 5, ch = gid & 31;
    int tok = tokens[row];
    tok = tok < 0 ? 0 : (tok >= VOCAB ? VOCAB-1 : tok);
    float4 v = *(const float4*)(emb + (size_t)tok*EMBED + ch*4);
    uint2 o; o.x = pack2(v.x, v.y); o.y = pack2(v.z, v.w);
    *(uint2*)(x_bf + (size_t)row*(EMBED/2) + ch*2) = o;
  } else if (bid < PB_BUCKET){                   // ---- bucket: 131,072 thr
    int eid = (bid-PB_CAST)*256 + tid;           // = B_SZ*NEDGE exactly
    int b = eid >> 13, i = eid & (NEDGE-1);
    const int* ei = edges + (size_t)b*2*NEDGE;
    int s = ei[i]         & (SEQ-1);
    int d = ei[NEDGE + i] & (SEQ-1);
    int gdst = (b << 11) | d;
    int slot = atomicAdd(&cnt[gdst], 1);
    if (slot < BCAP) bucket[(size_t)gdst*BCAP + slot] = (unsigned short)s;
    else {
      int o = atomicAdd(ovf_cnt, 1);
      if (o < OVCAP) ovf[o] = ((b << 11) | s) | (gdst << 16);
    }
  } else if (bid < PB_PRECM){                    // ---- precM: 2 hp per block
    int hp = (bid-PB_BUCKET)*2 + (tid >> 7);     // 0..255
    int e  = tid & 127;
    const float* w2 = Wupd + (size_t)hp*384 + 128;
    float acc = 0.f;
    for (int h1 = 0; h1 < HID; ++h1)
      acc += Wmsg[h1*EMBED + e] * w2[h1];
    MT[(size_t)hp*EMBED + e] = scrub(acc);
  } else if (bid < PB_CTAB){                     // ---- ctab (wave 0 only)
    if (tid < 64){
      int d = bid - PB_PRECM, lane = tid;        // d = 0..15
      float a0 = scrub(expf(-expf(A_log[(2*lane+0)*DSTATE + d])));
      float a1 = scrub(expf(-expf(A_log[(2*lane+1)*DSTATE + d])));
      float p0 = 1.f, p1 = 1.f;
      for (int k = 0; k < KTR; ++k){
        float s = p0 + p1;
        for (int off = 32; off; off >>= 1) s += __shfl_down(s, off);
        if (lane == 0) c_tab[k*DSTATE + d] = scrub(s * (1.0f/128.0f));
        p0 *= a0; p1 *= a1;
      }
    }
  } else {                                       // ---- precB (256 slots)
    int idx = tid;
    int c = idx >> 6, lane = idx & 63;
    int n = lane & 15;
    int kb = c*32 + (lane >> 4)*8;
    short v[8];
    #pragma unroll
    for (int jj = 0; jj < 8; ++jj) v[jj] = f2b(B_w[(size_t)n*EMBED + kb + jj]);
    *(s16x8*)(Bf + (size_t)idx*8) = *(s16x8*)v;
  }
}

// ---------------------------------------------------------------------------
// Fused bproj(MFMA) + conv + ssm + LayerNorm.
//   Occupancy redesign: 32 output rows / block, 512 threads (8 waves),
//   grid 1024 -> 4 blocks/CU x 8 waves = 32 waves/CU (was 8).
//   Halo = 64 rows recomputed -> bproj covers 96 rows = 6 tiles (waves 0-5).
//   blocks [1024,1040) : precW rider — combined weight into B-fragment order
__global__ __launch_bounds__(512, 8) void k_ssm_fused(
    const short* __restrict__ x_bf, const float* __restrict__ c_tab,
    const float* __restrict__ C_w, const float* __restrict__ D_skip,
    const float* __restrict__ ln_g, const float* __restrict__ ln_b,
    const short* __restrict__ Bf, const float* __restrict__ Wupd,
    const float* __restrict__ MT, unsigned int* __restrict__ h_out,
    short* __restrict__ Wcs){
  __shared__ float bsh[96][18];         // halo 64 + live 32; stride 18
  __shared__ float msh[32][18];
  __shared__ float Ct[DSTATE][EMBED+2];
  __shared__ float csh[KTR][DSTATE];
  int bid = blockIdx.x, tid = threadIdx.x;

  if (bid >= 1024){                     // ---- precW rider blocks (512 thr)
    int idx = (bid-1024)*512 + tid;     // 8192 fragment slots
    int c    = idx >> 10;
    int rem  = idx & 1023;
    int j    = rem >> 6;
    int lane = rem & 63;
    int n  = j*16 + (lane & 15);
    int kb = c*32 + (lane >> 4)*8;
    short v[8];
    #pragma unroll
    for (int jj = 0; jj < 8; ++jj){
      int k = kb + jj;
      float val = (k < 128) ? Wupd[(size_t)n*384 + k] : MT[(size_t)n*EMBED + (k-128)];
      v[jj] = f2b(val);
    }
    *(s16x8*)(Wcs + (size_t)idx*8) = *(s16x8*)v;
    return;
  }

  int b  = bid >> 6;                    // 64 blocks per batch
  int t0 = (bid & 63) * 32;
  for (int i = tid; i < DSTATE*EMBED; i += 512){
    int e = i >> 4, d = i & 15;         // coalesced read of C_w[e][d]
    Ct[d][e] = C_w[i];
  }
  for (int i = tid; i < KTR*DSTATE; i += 512)
    csh[i >> 4][i & 15] = c_tab[i];

  int wv = tid >> 6, lane = tid & 63;
  int m = lane & 15, lg = lane >> 4;

  // ---- bproj via MFMA: 6 tiles x 16 rows covering t0-64 .. t0+31
  const s16x8* Bp = (const s16x8*)Bf;
  if (wv < 6){
    int tile = wv;
    int trow = t0 - 64 + tile*16;
    f32x4 acc = (f32x4){0.f,0.f,0.f,0.f};
    if (trow >= 0){
      const short* xrow = x_bf + ((size_t)(b*SEQ + trow + m))*EMBED + lg*8;
      #pragma unroll
      for (int c = 0; c < 4; ++c){
        s16x8 a = *(const s16x8*)(xrow + c*32);
        acc = __builtin_amdgcn_mfma_f32_16x16x32_bf16(a, Bp[c*64 + lane], acc, 0, 0, 0);
      }
    }
    // C/D: col = lane&15 (=d), row = lg*4 + r ; zeros for trow<0 (halo)
    #pragma unroll
    for (int r = 0; r < 4; ++r)
      bsh[tile*16 + lg*4 + r][m] = scrub(acc[r]);
  }
  __syncthreads();

  // ---- conv from LDS: one (q,d) per thread; k ascending = same sum order
  {
    int d = tid & 15;
    int q = tid >> 4;                   // 0..31
    float acc = 0.f;
    #pragma unroll
    for (int k = 0; k < KTR; ++k)
      acc += csh[k][d] * bsh[64 + q - k][d];   // index 1..95, halo zeros
    msh[q][d] = scrub(acc);
  }
  __syncthreads();

  // ---- ssm + LN: each wave 4 rows; x from coalesced x_bf
  int e0 = lane*2;
  float2 dsk = *(const float2*)&D_skip[e0];
  float2 lgv = *(const float2*)&ln_g[e0];
  float2 lbv = *(const float2*)&ln_b[e0];
  const unsigned int* xb = (const unsigned int*)x_bf;
  for (int q = wv*4; q < wv*4+4; ++q){
    int row = b*SEQ + t0 + q;
    unsigned int xp = xb[(size_t)row*(EMBED/2) + lane];
    float x0 = lo2f(xp), x1 = hi2f(xp);
    float y0 = dsk.x*x0, y1 = dsk.y*x1;
    #pragma unroll
    for (int d = 0; d < DSTATE; ++d){
      float md = msh[q][d];             // wave-uniform -> LDS broadcast
      y0 += md * Ct[d][e0];
      y1 += md * Ct[d][e0+1];
    }
    y0 = scrub(y0); y1 = scrub(y1);
    float s = y0+y1, s2 = y0*y0 + y1*y1;
    for (int off = 32; off; off >>= 1){ s += __shfl_down(s,off); s2 += __shfl_down(s2,off); }
    s = __shfl(s, 0); s2 = __shfl(s2, 0);
    float mu  = s * (1.f/EMBED);
    float var = s2 * (1.f/EMBED) - mu*mu;
    float inv = rsqrtf(fmaxf(var, 0.f) + LN_EPS);
    float o0 = scrub(lgv.x*(y0-mu)*inv + lbv.x);
    float o1 = scrub(lgv.y*(y1-mu)*inv + lbv.y);
    h_out[(size_t)row*(EMBED/2) + lane] = pack2(o0, o1);
  }
}

// ---------------------------------------------------------------------------
// Fused gather + MFMA upd + relu + pool + (last block) classifier.
//   Occupancy redesign: 16 rows / block, grid 2048 (8 blocks/CU available).
//   Gather is wave-per-row (wave-uniform loop, coalesced 256B loads) into a
//   padded LDS tile; 4 waves then split the 16 j-tiles of the MFMA.
__global__ __launch_bounds__(256, 6) void k_upd_fused(
    const short* __restrict__ h, const int* __restrict__ cnt,
    const unsigned short* __restrict__ bucket,
    const int* __restrict__ ovf_cnt, const int* __restrict__ ovf,
    const short* __restrict__ Wcs, const float* __restrict__ Wupd_b,
    float* __restrict__ pool, int* __restrict__ done,
    const float* __restrict__ cls_w, const float* __restrict__ cls_b,
    float* __restrict__ out){
  // union: first as g tile [16][68] (padded: stride 68 words -> conflict-free
  // b128 fragment reads), later as last-block pool snapshot (4096 floats)
  __shared__ unsigned int smem[B_SZ*HID];      // 16 KB
  __shared__ int lastflag;
  int tid  = threadIdx.x;
  int wv   = tid >> 6, lane = tid & 63;
  int row0 = blockIdx.x * 16;
  int b    = row0 >> 11;                       // 16 | 2048: block batch-pure
  int m = lane & 15, lg = lane >> 4;

  // ---- gather: each wave 4 whole rows, coalesced (lane = uint word 0..63)
  const unsigned int* hb32 = (const unsigned int*)h + (size_t)(b*SEQ)*(EMBED/2);
  const unsigned int* h32  = (const unsigned int*)h;
  int on = *ovf_cnt; on = on > OVCAP ? OVCAP : on;   // ~always 0
  for (int i = 0; i < 4; ++i){
    int rloc = wv*4 + i;                       // 0..15
    int r = row0 + rloc;
    int n = cnt[r]; n = n > BCAP ? BCAP : n;
    const unsigned short* bk = bucket + (size_t)r*BCAP;
    float ax = 0.f, ay = 0.f;
    for (int t = 0; t < n; ++t){               // wave-uniform loop count
      unsigned int v = hb32[(size_t)bk[t]*(EMBED/2) + lane];
      ax += lo2f(v); ay += hi2f(v);
    }
    for (int idx = 0; idx < on; ++idx){
      int pk = ovf[idx];
      if (((pk >> 16) & 0x7fff) == r){
        unsigned int v = h32[(size_t)(pk & 0xffff)*(EMBED/2) + lane];
        ax += lo2f(v); ay += hi2f(v);
      }
    }
    smem[rloc*68 + lane] = pack2(scrub(ax), scrub(ay));
  }
  __syncthreads();

  // ---- A-fragments: h from global (L2-hot), g from LDS
  const short* hrow = h + (size_t)(row0+m)*EMBED + lg*8;
  s16x8 hfrag[4], gfrag[4];
  #pragma unroll
  for (int c = 0; c < 4; ++c){
    hfrag[c] = *(const s16x8*)(hrow + c*32);
    gfrag[c] = *(const s16x8*)&smem[m*68 + c*16 + lg*4];
  }

  // ---- MFMA: [h || g] @ Wcs^T; 4 waves split the 16 j-tiles (4 each)
  int j0 = wv*4;
  f32x4 acc[4];
  #pragma unroll
  for (int jj = 0; jj < 4; ++jj) acc[jj] = (f32x4){0.f,0.f,0.f,0.f};
  const s16x8* Bp = (const s16x8*)Wcs;
  #pragma unroll
  for (int c = 0; c < 8; ++c){
    s16x8 a = (c < 4) ? hfrag[c] : gfrag[c-4];
    #pragma unroll
    for (int jj = 0; jj < 4; ++jj){
      s16x8 bfr = Bp[(c*16 + j0 + jj)*64 + lane];
      acc[jj] = __builtin_amdgcn_mfma_f32_16x16x32_bf16(a, bfr, acc[jj], 0, 0, 0);
    }
  }

  // ---- relu + row-sum over the 16 rows; one atomic per (j,n) per block
  #pragma unroll
  for (int jj = 0; jj < 4; ++jj){
    int nn = (j0 + jj)*16 + m;
    float bias = Wupd_b[nn];
    float v = 0.f;
    #pragma unroll
    for (int rr = 0; rr < 4; ++rr) v += fmaxf(acc[jj][rr] + bias, 0.f);
    v += __shfl_down(v, 32);
    v += __shfl_down(v, 16);
    if (lane < 16) atomicAdd(&pool[b*HID + nn], scrub(v));
  }
  __threadfence();                        // release our pool adds
  __syncthreads();                        // all waves done with smem/gfrag
  if (tid == 0){
    int prev = atomicAdd(done, 1);
    lastflag = (prev == (int)gridDim.x - 1);
  }
  __syncthreads();
  if (!lastflag) return;

  // ---- last block: classifier (coherent pool loads across XCD L2s)
  float* plds = (float*)smem;             // overlay: g tile no longer needed
  for (int i = tid; i < B_SZ*HID; i += 256)
    plds[i] = __hip_atomic_load(&pool[i], __ATOMIC_RELAXED, __HIP_MEMORY_SCOPE_AGENT);
  __syncthreads();
  if (tid < B_SZ*NCLS){
    int bb = tid / NCLS, c = tid - bb*NCLS;
    const float* w = cls_w + c*HID;
    float s = 0.f;
    for (int h1 = 0; h1 < HID; ++h1) s += plds[bb*HID + h1] * w[h1];
    out[tid] = scrub(s * (1.0f/SEQ) + cls_b[c]);
  }
}

// ---------------------------------------------------------------------------
extern "C" void kernel_launch(void* const* d_in, const int* in_sizes, int n_in,
                              void* d_out, int out_size, void* d_ws, size_t ws_size,
                              hipStream_t stream) {
  const int*   tokens = (const int*)d_in[0];
  const int*   edges  = (const int*)d_in[2];
  const float* emb    = (const float*)d_in[3];
  const float* A_log  = (const float*)d_in[4];
  const float* B_w    = (const float*)d_in[5];
  const float* C_w    = (const float*)d_in[6];
  const float* D_skip = (const float*)d_in[7];
  const float* ln_g   = (const float*)d_in[8];
  const float* ln_b   = (const float*)d_in[9];
  const float* Wmsg   = (const float*)d_in[10];
  const float* Wupd   = (const float*)d_in[11];
  const float* Wupd_b = (const float*)d_in[12];
  const float* cls_w  = (const float*)d_in[13];
  const float* cls_b  = (const float*)d_in[14];
  float* out = (float*)d_out;

  // workspace layout (~18.4 MB)
  char* ws = (char*)d_ws;
  float* c_tab = (float*)ws;  ws += 16*1024;                 // 4 KB used
  float* MT    = (float*)ws;  ws += (size_t)HID*EMBED*4;     // 128 KB
  short* Wcs   = (short*)ws;  ws += (size_t)HID*HID*2;       // 128 KB
  short* Bf    = (short*)ws;  ws += 16*1024;                 // 4 KB used
  char*  zbase = ws;
  float* pool  = (float*)ws;  ws += (size_t)B_SZ*HID*4;      // 16 KB
  int*   cnt   = (int*)ws;    ws += (size_t)NROW*4;          // 128 KB
  int*   ovf_cnt = (int*)ws;  ws += 64;
  int*   done  = (int*)ws;    ws += 64;
  int*   ovf   = (int*)ws;    ws += OVCAP*4;                 // 4 KB
  size_t zlen = (size_t)((char*)ws - zbase);
  unsigned short* bucket = (unsigned short*)ws; ws += (size_t)NROW*BCAP*2; // 2 MB
  short* x_bf  = (short*)ws;  ws += (size_t)NROW*EMBED*2;    // 8 MB
  short* h_bf  = (short*)ws;  ws += (size_t)NROW*EMBED*2;    // 8 MB

  hipMemsetAsync(zbase, 0, zlen, stream);
  hipLaunchKernelGGL(k_prep, dim3(PB_TOTAL), dim3(256), 0, stream,
                     tokens, emb, A_log, B_w, Wmsg, Wupd, edges,
                     c_tab, Bf, MT, (unsigned int*)x_bf, cnt, bucket, ovf_cnt, ovf);
  hipLaunchKernelGGL(k_ssm_fused, dim3(1040), dim3(512), 0, stream,
                     x_bf, c_tab, C_w, D_skip, ln_g, ln_b, Bf, Wupd, MT,
                     (unsigned int*)h_bf, Wcs);
  hipLaunchKernelGGL(k_upd_fused, dim3(NROW/16), dim3(256), 0, stream,
                     h_bf, cnt, bucket, ovf_cnt, ovf, Wcs, Wupd_b,
                     pool, done, cls_w, cls_b, out);
}

// Round 4
// 220.362 us; speedup vs baseline: 1.6768x; 1.6768x over previous
//
#include <hip/hip_runtime.h>

#define B_SZ   16
#define SEQ    2048
#define VOCAB  50257
#define EMBED  128
#define DSTATE 16
#define HID    256
#define NCLS   10
#define NEDGE  8192
#define KTR    64          // scan truncation: A<=0.55 -> A^64 < 2e-17
#define LN_EPS 1e-5f
#define NROW   (B_SZ*SEQ)  // 32768
#define BCAP   32          // bucket capacity per dst (Poisson lambda=4)
#define OVCAP  1024        // overflow fallback capacity

// k_prep phase block ranges
#define PB_CAST   4096                  // NROW*32/256
#define PB_BUCKET (PB_CAST + 512)       // B_SZ*NEDGE/256 = 512
#define PB_PRECM  (PB_BUCKET + 128)     // 256 hp, 2 per block
#define PB_CTAB   (PB_PRECM + 16)       // 16 d
#define PB_TOTAL  (PB_CTAB + 1)         // +1 precB

typedef float  f32x4 __attribute__((ext_vector_type(4)));
typedef short  s16x8 __attribute__((ext_vector_type(8)));

__device__ __forceinline__ float scrub(float x){
  return (x == x && fabsf(x) < 1e30f) ? x : 0.f;
}
// fp32 -> bf16 bits, round-to-nearest-even
__device__ __forceinline__ short f2b(float f){
  unsigned int u = __float_as_uint(f);
  unsigned int r = (u + 0x7fffu + ((u >> 16) & 1u)) >> 16;
  return (short)r;
}
__device__ __forceinline__ unsigned int pack2(float a, float b){
  return (unsigned int)(unsigned short)f2b(a)
       | ((unsigned int)(unsigned short)f2b(b) << 16);
}
__device__ __forceinline__ float lo2f(unsigned int v){ return __uint_as_float(v << 16); }
__device__ __forceinline__ float hi2f(unsigned int v){ return __uint_as_float(v & 0xffff0000u); }

// ---------------------------------------------------------------------------
// Heterogeneous prep kernel: all phases mutually independent. (round-0 exact)
__global__ __launch_bounds__(256) void k_prep(
    const int* __restrict__ tokens, const float* __restrict__ emb,
    const float* __restrict__ A_log, const float* __restrict__ B_w,
    const float* __restrict__ Wmsg, const float* __restrict__ Wupd,
    const int* __restrict__ edges,
    float* __restrict__ c_tab, short* __restrict__ Bf, float* __restrict__ MT,
    unsigned int* __restrict__ x_bf, int* __restrict__ cnt,
    unsigned short* __restrict__ bucket, int* __restrict__ ovf_cnt,
    int* __restrict__ ovf){
  int bid = blockIdx.x, tid = threadIdx.x;
  if (bid < PB_CAST){                            // ---- cast: 1,048,576 thr
    int gid = bid*256 + tid;                     // = NROW*32 exactly
    int row = gid >> 5, ch = gid & 31;
    int tok = tokens[row];
    tok = tok < 0 ? 0 : (tok >= VOCAB ? VOCAB-1 : tok);
    float4 v = *(const float4*)(emb + (size_t)tok*EMBED + ch*4);
    uint2 o; o.x = pack2(v.x, v.y); o.y = pack2(v.z, v.w);
    *(uint2*)(x_bf + (size_t)row*(EMBED/2) + ch*2) = o;
  } else if (bid < PB_BUCKET){                   // ---- bucket: 131,072 thr
    int eid = (bid-PB_CAST)*256 + tid;           // = B_SZ*NEDGE exactly
    int b = eid >> 13, i = eid & (NEDGE-1);
    const int* ei = edges + (size_t)b*2*NEDGE;
    int s = ei[i]         & (SEQ-1);
    int d = ei[NEDGE + i] & (SEQ-1);
    int gdst = (b << 11) | d;
    int slot = atomicAdd(&cnt[gdst], 1);
    if (slot < BCAP) bucket[(size_t)gdst*BCAP + slot] = (unsigned short)s;
    else {
      int o = atomicAdd(ovf_cnt, 1);
      if (o < OVCAP) ovf[o] = ((b << 11) | s) | (gdst << 16);
    }
  } else if (bid < PB_PRECM){                    // ---- precM: 2 hp per block
    int hp = (bid-PB_BUCKET)*2 + (tid >> 7);     // 0..255
    int e  = tid & 127;
    const float* w2 = Wupd + (size_t)hp*384 + 128;
    float acc = 0.f;
    for (int h1 = 0; h1 < HID; ++h1)
      acc += Wmsg[h1*EMBED + e] * w2[h1];
    MT[(size_t)hp*EMBED + e] = scrub(acc);
  } else if (bid < PB_CTAB){                     // ---- ctab (wave 0 only)
    if (tid < 64){
      int d = bid - PB_PRECM, lane = tid;        // d = 0..15
      float a0 = scrub(expf(-expf(A_log[(2*lane+0)*DSTATE + d])));
      float a1 = scrub(expf(-expf(A_log[(2*lane+1)*DSTATE + d])));
      float p0 = 1.f, p1 = 1.f;
      for (int k = 0; k < KTR; ++k){
        float s = p0 + p1;
        for (int off = 32; off; off >>= 1) s += __shfl_down(s, off);
        if (lane == 0) c_tab[k*DSTATE + d] = scrub(s * (1.0f/128.0f));
        p0 *= a0; p1 *= a1;
      }
    }
  } else {                                       // ---- precB (256 slots)
    int idx = tid;
    int c = idx >> 6, lane = idx & 63;
    int n = lane & 15;
    int kb = c*32 + (lane >> 4)*8;
    short v[8];
    #pragma unroll
    for (int jj = 0; jj < 8; ++jj) v[jj] = f2b(B_w[(size_t)n*EMBED + kb + jj]);
    *(s16x8*)(Bf + (size_t)idx*8) = *(s16x8*)v;
  }
}

// ---------------------------------------------------------------------------
// Fused bproj(MFMA) + conv + ssm + LayerNorm; round-0 structure (544 blocks,
// 256 thr) with round-1's register-sliding-window conv (4x fewer LDS reads).
__global__ __launch_bounds__(256) void k_ssm_fused(
    const short* __restrict__ x_bf, const float* __restrict__ c_tab,
    const float* __restrict__ C_w, const float* __restrict__ D_skip,
    const float* __restrict__ ln_g, const float* __restrict__ ln_b,
    const short* __restrict__ Bf, const float* __restrict__ Wupd,
    const float* __restrict__ MT, unsigned int* __restrict__ h_out,
    short* __restrict__ Wcs){
  __shared__ float bsh[128][18];        // stride 18: 2-way (free) banking
  __shared__ float msh[64][18];
  __shared__ float Ct[DSTATE][EMBED+2];
  __shared__ float csh[KTR][DSTATE];
  int bid = blockIdx.x, tid = threadIdx.x;

  if (bid >= 512){                      // ---- precW rider blocks
    int idx = (bid-512)*256 + tid;      // 8192 fragment slots
    int c    = idx >> 10;
    int rem  = idx & 1023;
    int j    = rem >> 6;
    int lane = rem & 63;
    int n  = j*16 + (lane & 15);
    int kb = c*32 + (lane >> 4)*8;
    short v[8];
    #pragma unroll
    for (int jj = 0; jj < 8; ++jj){
      int k = kb + jj;
      float val = (k < 128) ? Wupd[(size_t)n*384 + k] : MT[(size_t)n*EMBED + (k-128)];
      v[jj] = f2b(val);
    }
    *(s16x8*)(Wcs + (size_t)idx*8) = *(s16x8*)v;
    return;
  }

  int b  = bid >> 5;
  int t0 = (bid & 31) * 64;
  for (int i = tid; i < DSTATE*EMBED; i += 256){
    int e = i >> 4, d = i & 15;         // coalesced read of C_w[e][d]
    Ct[d][e] = C_w[i];
  }
  for (int i = tid; i < KTR*DSTATE; i += 256)
    csh[i >> 4][i & 15] = c_tab[i];

  int wv = tid >> 6, lane = tid & 63;
  int m = lane & 15, lg = lane >> 4;

  // ---- bproj via MFMA: 8 tiles x 16 rows covering t0-64 .. t0+63
  const s16x8* Bp = (const s16x8*)Bf;
  #pragma unroll
  for (int tt = 0; tt < 2; ++tt){
    int tile = wv*2 + tt;               // 0..7
    int trow = t0 - 64 + tile*16;
    f32x4 acc = (f32x4){0.f,0.f,0.f,0.f};
    if (trow >= 0){
      const short* xrow = x_bf + ((size_t)(b*SEQ + trow + m))*EMBED + lg*8;
      #pragma unroll
      for (int c = 0; c < 4; ++c){
        s16x8 a = *(const s16x8*)(xrow + c*32);
        acc = __builtin_amdgcn_mfma_f32_16x16x32_bf16(a, Bp[c*64 + lane], acc, 0, 0, 0);
      }
    }
    // C/D: col = lane&15 (=d), row = lg*4 + r
    #pragma unroll
    for (int r = 0; r < 4; ++r)
      bsh[tile*16 + lg*4 + r][m] = scrub(acc[r]);
  }
  __syncthreads();

  // ---- conv from LDS: register-sliding window, 4 consecutive q per thread.
  // Halo rows for t0=0 blocks are exact zeros in bsh, so the full k=0..63 sum
  // is bit-identical to the kmax-trimmed loop (trimmed terms were c*0).
  {
    int d  = tid & 15;
    int qb = (tid >> 4) * 4;            // 0,4,...,60
    float a0=0.f, a1=0.f, a2=0.f, a3=0.f;
    float w0 = bsh[64+qb+0][d];
    float w1 = bsh[64+qb+1][d];
    float w2 = bsh[64+qb+2][d];
    float w3 = bsh[64+qb+3][d];
    #pragma unroll
    for (int k = 0; k < KTR; ++k){
      float c = csh[k][d];
      a0 += c*w0; a1 += c*w1; a2 += c*w2; a3 += c*w3;
      w3 = w2; w2 = w1; w1 = w0;
      w0 = (k+1 < KTR) ? bsh[64+qb-k-1][d] : 0.f;
    }
    msh[qb+0][d] = scrub(a0); msh[qb+1][d] = scrub(a1);
    msh[qb+2][d] = scrub(a2); msh[qb+3][d] = scrub(a3);
  }
  __syncthreads();

  // ---- ssm + LN: each wave 16 rows; x from coalesced x_bf
  int e0 = lane*2;
  float2 dsk = *(const float2*)&D_skip[e0];
  float2 lgv = *(const float2*)&ln_g[e0];
  float2 lbv = *(const float2*)&ln_b[e0];
  const unsigned int* xb = (const unsigned int*)x_bf;
  for (int q = wv*16; q < wv*16+16; ++q){
    int row = b*SEQ + t0 + q;
    unsigned int xp = xb[(size_t)row*(EMBED/2) + lane];
    float x0 = lo2f(xp), x1 = hi2f(xp);
    float y0 = dsk.x*x0, y1 = dsk.y*x1;
    #pragma unroll
    for (int d = 0; d < DSTATE; ++d){
      float md = msh[q][d];             // wave-uniform -> LDS broadcast
      y0 += md * Ct[d][e0];
      y1 += md * Ct[d][e0+1];
    }
    y0 = scrub(y0); y1 = scrub(y1);
    float s = y0+y1, s2 = y0*y0 + y1*y1;
    for (int off = 32; off; off >>= 1){ s += __shfl_down(s,off); s2 += __shfl_down(s2,off); }
    s = __shfl(s, 0); s2 = __shfl(s2, 0);
    float mu  = s * (1.f/EMBED);
    float var = s2 * (1.f/EMBED) - mu*mu;
    float inv = rsqrtf(fmaxf(var, 0.f) + LN_EPS);
    float o0 = scrub(lgv.x*(y0-mu)*inv + lbv.x);
    float o1 = scrub(lgv.y*(y1-mu)*inv + lbv.y);
    h_out[(size_t)row*(EMBED/2) + lane] = pack2(o0, o1);
  }
}

// ---------------------------------------------------------------------------
// g[gdst][:] = sum over bucketed srcs of h[b*SEQ+src][:]. One wave per dst row.
// (round-0 exact: 8192 blocks, wave-uniform coalesced loads, high TLP)
__global__ __launch_bounds__(256) void k_gather(
    const int* __restrict__ cnt, const unsigned short* __restrict__ bucket,
    const int* __restrict__ ovf_cnt, const int* __restrict__ ovf,
    const unsigned int* __restrict__ h, unsigned int* __restrict__ g){
  int wv = threadIdx.x >> 6, lane = threadIdx.x & 63;
  int gdst = blockIdx.x*4 + wv;
  int n = cnt[gdst]; n = n > BCAP ? BCAP : n;
  int b = gdst >> 11;
  const unsigned int* hb = h + (size_t)b*SEQ*(EMBED/2);
  const unsigned short* bk = bucket + (size_t)gdst*BCAP;
  float ax = 0.f, ay = 0.f;
  for (int i = 0; i < n; ++i){
    unsigned int v = hb[(size_t)bk[i]*(EMBED/2) + lane];
    ax += lo2f(v); ay += hi2f(v);
  }
  int on = *ovf_cnt; on = on > OVCAP ? OVCAP : on;   // ~always 0
  for (int idx = 0; idx < on; ++idx){
    int pk = ovf[idx];
    if (((pk >> 16) & 0x7fff) == gdst){
      unsigned int v = h[(size_t)(pk & 0xffff)*(EMBED/2) + lane];
      ax += lo2f(v); ay += hi2f(v);
    }
  }
  g[(size_t)gdst*(EMBED/2) + lane] = pack2(scrub(ax), scrub(ay));
}

// ---------------------------------------------------------------------------
// MFMA upd+relu+pool (round-0 shape: one wave per 16 rows, acc[16], 512
// blocks) + LDS psum reduce (4x fewer pool atomics) + folded classifier.
__global__ __launch_bounds__(256) void k_upd_fused(
    const short* __restrict__ h, const short* __restrict__ g,
    const short* __restrict__ Wcs, const float* __restrict__ Wupd_b,
    float* __restrict__ pool, int* __restrict__ done,
    const float* __restrict__ cls_w, const float* __restrict__ cls_b,
    float* __restrict__ out){
  __shared__ float psum[4][HID];          // 4 KB
  __shared__ float plds[B_SZ*HID];        // 16 KB (last-block snapshot)
  __shared__ int   lastflag;
  int tid = threadIdx.x;
  int wv = tid >> 6, lane = tid & 63;
  int wave = blockIdx.x*4 + wv;
  int row0 = wave * 16;
  int b = row0 >> 11;                      // uniform per block (64 | 2048)
  int m = lane & 15, lg = lane >> 4;
  const short* hrow = h + (size_t)(row0+m)*EMBED + lg*8;
  const short* grow = g + (size_t)(row0+m)*EMBED + lg*8;

  f32x4 acc[16];
  #pragma unroll
  for (int j = 0; j < 16; ++j) acc[j] = (f32x4){0.f,0.f,0.f,0.f};

  const s16x8* Bp = (const s16x8*)Wcs;
  #pragma unroll
  for (int c = 0; c < 8; ++c){
    s16x8 a = (c < 4) ? *(const s16x8*)(hrow + c*32)
                      : *(const s16x8*)(grow + (c-4)*32);
    #pragma unroll
    for (int j = 0; j < 16; ++j){
      s16x8 bfr = Bp[(c*16 + j)*64 + lane];
      acc[j] = __builtin_amdgcn_mfma_f32_16x16x32_bf16(a, bfr, acc[j], 0, 0, 0);
    }
  }

  // C/D layout: col = lane&15, row = (lane>>4)*4 + reg
  #pragma unroll
  for (int j = 0; j < 16; ++j){
    int n = j*16 + m;
    float bias = Wupd_b[n];
    float v = 0.f;
    #pragma unroll
    for (int r = 0; r < 4; ++r) v += fmaxf(acc[j][r] + bias, 0.f);
    v += __shfl_down(v, 32);
    v += __shfl_down(v, 16);
    if (lane < 16) psum[wv][n] = scrub(v);
  }
  __syncthreads();
  if (tid < HID){
    float t = psum[0][tid] + psum[1][tid] + psum[2][tid] + psum[3][tid];
    atomicAdd(&pool[b*HID + tid], t);
  }
  __threadfence();                        // release our pool adds
  __syncthreads();
  if (tid == 0){
    int prev = atomicAdd(done, 1);
    lastflag = (prev == (int)gridDim.x - 1);
  }
  __syncthreads();
  if (!lastflag) return;

  // ---- last block: classifier (coherent pool loads across XCD L2s)
  for (int i = tid; i < B_SZ*HID; i += 256)
    plds[i] = __hip_atomic_load(&pool[i], __ATOMIC_RELAXED, __HIP_MEMORY_SCOPE_AGENT);
  __syncthreads();
  if (tid < B_SZ*NCLS){
    int bb = tid / NCLS, c = tid - bb*NCLS;
    const float* w = cls_w + c*HID;
    float s = 0.f;
    for (int h1 = 0; h1 < HID; ++h1) s += plds[bb*HID + h1] * w[h1];
    out[tid] = scrub(s * (1.0f/SEQ) + cls_b[c]);
  }
}

// ---------------------------------------------------------------------------
extern "C" void kernel_launch(void* const* d_in, const int* in_sizes, int n_in,
                              void* d_out, int out_size, void* d_ws, size_t ws_size,
                              hipStream_t stream) {
  const int*   tokens = (const int*)d_in[0];
  const int*   edges  = (const int*)d_in[2];
  const float* emb    = (const float*)d_in[3];
  const float* A_log  = (const float*)d_in[4];
  const float* B_w    = (const float*)d_in[5];
  const float* C_w    = (const float*)d_in[6];
  const float* D_skip = (const float*)d_in[7];
  const float* ln_g   = (const float*)d_in[8];
  const float* ln_b   = (const float*)d_in[9];
  const float* Wmsg   = (const float*)d_in[10];
  const float* Wupd   = (const float*)d_in[11];
  const float* Wupd_b = (const float*)d_in[12];
  const float* cls_w  = (const float*)d_in[13];
  const float* cls_b  = (const float*)d_in[14];
  float* out = (float*)d_out;

  // workspace layout (~26.5 MB)
  char* ws = (char*)d_ws;
  float* c_tab = (float*)ws;  ws += 16*1024;                 // 4 KB used
  float* MT    = (float*)ws;  ws += (size_t)HID*EMBED*4;     // 128 KB
  short* Wcs   = (short*)ws;  ws += (size_t)HID*HID*2;       // 128 KB
  short* Bf    = (short*)ws;  ws += 16*1024;                 // 4 KB used
  char*  zbase = ws;
  float* pool  = (float*)ws;  ws += (size_t)B_SZ*HID*4;      // 16 KB
  int*   cnt   = (int*)ws;    ws += (size_t)NROW*4;          // 128 KB
  int*   ovf_cnt = (int*)ws;  ws += 64;
  int*   done  = (int*)ws;    ws += 64;
  int*   ovf   = (int*)ws;    ws += OVCAP*4;                 // 4 KB
  size_t zlen = (size_t)((char*)ws - zbase);
  unsigned short* bucket = (unsigned short*)ws; ws += (size_t)NROW*BCAP*2; // 2 MB
  short* x_bf  = (short*)ws;  ws += (size_t)NROW*EMBED*2;    // 8 MB
  short* h_bf  = (short*)ws;  ws += (size_t)NROW*EMBED*2;    // 8 MB
  short* g_bf  = (short*)ws;  ws += (size_t)NROW*EMBED*2;    // 8 MB

  hipMemsetAsync(zbase, 0, zlen, stream);
  hipLaunchKernelGGL(k_prep, dim3(PB_TOTAL), dim3(256), 0, stream,
                     tokens, emb, A_log, B_w, Wmsg, Wupd, edges,
                     c_tab, Bf, MT, (unsigned int*)x_bf, cnt, bucket, ovf_cnt, ovf);
  hipLaunchKernelGGL(k_ssm_fused, dim3(544), dim3(256), 0, stream,
                     x_bf, c_tab, C_w, D_skip, ln_g, ln_b, Bf, Wupd, MT,
                     (unsigned int*)h_bf, Wcs);
  hipLaunchKernelGGL(k_gather, dim3(NROW/4), dim3(256), 0, stream,
                     cnt, bucket, ovf_cnt, ovf, (const unsigned int*)h_bf,
                     (unsigned int*)g_bf);
  hipLaunchKernelGGL(k_upd_fused, dim3(NROW/64), dim3(256), 0, stream,
                     h_bf, g_bf, Wcs, Wupd_b, pool, done, cls_w, cls_b, out);
}

// Round 5
// 193.575 us; speedup vs baseline: 1.9088x; 1.1384x over previous
//
#include <hip/hip_runtime.h>

#define B_SZ   16
#define SEQ    2048
#define VOCAB  50257
#define EMBED  128
#define DSTATE 16
#define HID    256
#define NCLS   10
#define NEDGE  8192
#define KTR    64          // scan truncation: A<=0.55 -> A^64 < 2e-17
#define LN_EPS 1e-5f
#define NROW   (B_SZ*SEQ)  // 32768
#define BCAP   32          // bucket capacity per dst (Poisson lambda=4)
#define OVCAP  1024        // overflow fallback capacity

// k_prep phase block ranges
#define PB_CAST   4096                  // NROW*32/256
#define PB_BUCKET (PB_CAST + 512)       // B_SZ*NEDGE/256 = 512
#define PB_PRECM  (PB_BUCKET + 128)     // 256 hp, 2 per block
#define PB_CTAB   (PB_PRECM + 16)       // 16 d
#define PB_TOTAL  (PB_CTAB + 1)         // +1 precB

typedef float  f32x4 __attribute__((ext_vector_type(4)));
typedef short  s16x8 __attribute__((ext_vector_type(8)));

__device__ __forceinline__ float scrub(float x){
  return (x == x && fabsf(x) < 1e30f) ? x : 0.f;
}
// fp32 -> bf16 bits, round-to-nearest-even
__device__ __forceinline__ short f2b(float f){
  unsigned int u = __float_as_uint(f);
  unsigned int r = (u + 0x7fffu + ((u >> 16) & 1u)) >> 16;
  return (short)r;
}
__device__ __forceinline__ unsigned int pack2(float a, float b){
  return (unsigned int)(unsigned short)f2b(a)
       | ((unsigned int)(unsigned short)f2b(b) << 16);
}
__device__ __forceinline__ float lo2f(unsigned int v){ return __uint_as_float(v << 16); }
__device__ __forceinline__ float hi2f(unsigned int v){ return __uint_as_float(v & 0xffff0000u); }

// ---------------------------------------------------------------------------
// Heterogeneous prep kernel: all phases mutually independent. (round-0 exact)
__global__ __launch_bounds__(256) void k_prep(
    const int* __restrict__ tokens, const float* __restrict__ emb,
    const float* __restrict__ A_log, const float* __restrict__ B_w,
    const float* __restrict__ Wmsg, const float* __restrict__ Wupd,
    const int* __restrict__ edges,
    float* __restrict__ c_tab, short* __restrict__ Bf, float* __restrict__ MT,
    unsigned int* __restrict__ x_bf, int* __restrict__ cnt,
    unsigned short* __restrict__ bucket, int* __restrict__ ovf_cnt,
    int* __restrict__ ovf){
  int bid = blockIdx.x, tid = threadIdx.x;
  if (bid < PB_CAST){                            // ---- cast: 1,048,576 thr
    int gid = bid*256 + tid;                     // = NROW*32 exactly
    int row = gid >> 5, ch = gid & 31;
    int tok = tokens[row];
    tok = tok < 0 ? 0 : (tok >= VOCAB ? VOCAB-1 : tok);
    float4 v = *(const float4*)(emb + (size_t)tok*EMBED + ch*4);
    uint2 o; o.x = pack2(v.x, v.y); o.y = pack2(v.z, v.w);
    *(uint2*)(x_bf + (size_t)row*(EMBED/2) + ch*2) = o;
  } else if (bid < PB_BUCKET){                   // ---- bucket: 131,072 thr
    int eid = (bid-PB_CAST)*256 + tid;           // = B_SZ*NEDGE exactly
    int b = eid >> 13, i = eid & (NEDGE-1);
    const int* ei = edges + (size_t)b*2*NEDGE;
    int s = ei[i]         & (SEQ-1);
    int d = ei[NEDGE + i] & (SEQ-1);
    int gdst = (b << 11) | d;
    int slot = atomicAdd(&cnt[gdst], 1);
    if (slot < BCAP) bucket[(size_t)gdst*BCAP + slot] = (unsigned short)s;
    else {
      int o = atomicAdd(ovf_cnt, 1);
      if (o < OVCAP) ovf[o] = ((b << 11) | s) | (gdst << 16);
    }
  } else if (bid < PB_PRECM){                    // ---- precM: 2 hp per block
    int hp = (bid-PB_BUCKET)*2 + (tid >> 7);     // 0..255
    int e  = tid & 127;
    const float* w2 = Wupd + (size_t)hp*384 + 128;
    float acc = 0.f;
    for (int h1 = 0; h1 < HID; ++h1)
      acc += Wmsg[h1*EMBED + e] * w2[h1];
    MT[(size_t)hp*EMBED + e] = scrub(acc);
  } else if (bid < PB_CTAB){                     // ---- ctab (wave 0 only)
    if (tid < 64){
      int d = bid - PB_PRECM, lane = tid;        // d = 0..15
      float a0 = scrub(expf(-expf(A_log[(2*lane+0)*DSTATE + d])));
      float a1 = scrub(expf(-expf(A_log[(2*lane+1)*DSTATE + d])));
      float p0 = 1.f, p1 = 1.f;
      for (int k = 0; k < KTR; ++k){
        float s = p0 + p1;
        for (int off = 32; off; off >>= 1) s += __shfl_down(s, off);
        if (lane == 0) c_tab[k*DSTATE + d] = scrub(s * (1.0f/128.0f));
        p0 *= a0; p1 *= a1;
      }
    }
  } else {                                       // ---- precB (256 slots)
    int idx = tid;
    int c = idx >> 6, lane = idx & 63;
    int n = lane & 15;
    int kb = c*32 + (lane >> 4)*8;
    short v[8];
    #pragma unroll
    for (int jj = 0; jj < 8; ++jj) v[jj] = f2b(B_w[(size_t)n*EMBED + kb + jj]);
    *(s16x8*)(Bf + (size_t)idx*8) = *(s16x8*)v;
  }
}

// ---------------------------------------------------------------------------
// Fused bproj(MFMA) + conv + ssm + LayerNorm; b,m only in LDS. (round-0 exact)
//   blocks [0,512)   : 64 rows each (one batch, 64-row halo recomputed)
//   blocks [512,544) : precW — combined weight into B-fragment order
__global__ __launch_bounds__(256) void k_ssm_fused(
    const short* __restrict__ x_bf, const float* __restrict__ c_tab,
    const float* __restrict__ C_w, const float* __restrict__ D_skip,
    const float* __restrict__ ln_g, const float* __restrict__ ln_b,
    const short* __restrict__ Bf, const float* __restrict__ Wupd,
    const float* __restrict__ MT, unsigned int* __restrict__ h_out,
    short* __restrict__ Wcs){
  __shared__ float bsh[128][18];        // stride 18: 2-way (free) banking
  __shared__ float msh[64][18];
  __shared__ float Ct[DSTATE][EMBED+2];
  __shared__ float csh[KTR][DSTATE];
  int bid = blockIdx.x, tid = threadIdx.x;

  if (bid >= 512){                      // ---- precW rider blocks
    int idx = (bid-512)*256 + tid;      // 8192 fragment slots
    int c    = idx >> 10;
    int rem  = idx & 1023;
    int j    = rem >> 6;
    int lane = rem & 63;
    int n  = j*16 + (lane & 15);
    int kb = c*32 + (lane >> 4)*8;
    short v[8];
    #pragma unroll
    for (int jj = 0; jj < 8; ++jj){
      int k = kb + jj;
      float val = (k < 128) ? Wupd[(size_t)n*384 + k] : MT[(size_t)n*EMBED + (k-128)];
      v[jj] = f2b(val);
    }
    *(s16x8*)(Wcs + (size_t)idx*8) = *(s16x8*)v;
    return;
  }

  int b  = bid >> 5;
  int t0 = (bid & 31) * 64;
  for (int i = tid; i < DSTATE*EMBED; i += 256){
    int e = i >> 4, d = i & 15;         // coalesced read of C_w[e][d]
    Ct[d][e] = C_w[i];
  }
  for (int i = tid; i < KTR*DSTATE; i += 256)
    csh[i >> 4][i & 15] = c_tab[i];

  int wv = tid >> 6, lane = tid & 63;
  int m = lane & 15, lg = lane >> 4;

  // ---- bproj via MFMA: 8 tiles x 16 rows covering t0-64 .. t0+63
  const s16x8* Bp = (const s16x8*)Bf;
  #pragma unroll
  for (int tt = 0; tt < 2; ++tt){
    int tile = wv*2 + tt;               // 0..7
    int trow = t0 - 64 + tile*16;
    f32x4 acc = (f32x4){0.f,0.f,0.f,0.f};
    if (trow >= 0){
      const short* xrow = x_bf + ((size_t)(b*SEQ + trow + m))*EMBED + lg*8;
      #pragma unroll
      for (int c = 0; c < 4; ++c){
        s16x8 a = *(const s16x8*)(xrow + c*32);
        acc = __builtin_amdgcn_mfma_f32_16x16x32_bf16(a, Bp[c*64 + lane], acc, 0, 0, 0);
      }
    }
    // C/D: col = lane&15 (=d), row = lg*4 + r
    #pragma unroll
    for (int r = 0; r < 4; ++r)
      bsh[tile*16 + lg*4 + r][m] = scrub(acc[r]);
  }
  __syncthreads();

  // ---- conv from LDS (taps in csh, uniform-address broadcast)
  {
    int d = tid & 15;
    #pragma unroll
    for (int it = 0; it < 4; ++it){
      int q = (tid + it*256) >> 4;      // 0..63
      int t = t0 + q;
      int base = 64 + q;
      int kmax = (t+1 < KTR) ? t+1 : KTR;
      float acc = 0.f;
      for (int k = 0; k < kmax; ++k) acc += csh[k][d] * bsh[base-k][d];
      msh[q][d] = scrub(acc);
    }
  }
  __syncthreads();

  // ---- ssm + LN: each wave 16 rows; x from coalesced x_bf
  int e0 = lane*2;
  float2 dsk = *(const float2*)&D_skip[e0];
  float2 lgv = *(const float2*)&ln_g[e0];
  float2 lbv = *(const float2*)&ln_b[e0];
  const unsigned int* xb = (const unsigned int*)x_bf;
  for (int q = wv*16; q < wv*16+16; ++q){
    int row = b*SEQ + t0 + q;
    unsigned int xp = xb[(size_t)row*(EMBED/2) + lane];
    float x0 = lo2f(xp), x1 = hi2f(xp);
    float y0 = dsk.x*x0, y1 = dsk.y*x1;
    #pragma unroll
    for (int d = 0; d < DSTATE; ++d){
      float md = msh[q][d];             // wave-uniform -> LDS broadcast
      y0 += md * Ct[d][e0];
      y1 += md * Ct[d][e0+1];
    }
    y0 = scrub(y0); y1 = scrub(y1);
    float s = y0+y1, s2 = y0*y0 + y1*y1;
    for (int off = 32; off; off >>= 1){ s += __shfl_down(s,off); s2 += __shfl_down(s2,off); }
    s = __shfl(s, 0); s2 = __shfl(s2, 0);
    float mu  = s * (1.f/EMBED);
    float var = s2 * (1.f/EMBED) - mu*mu;
    float inv = rsqrtf(fmaxf(var, 0.f) + LN_EPS);
    float o0 = scrub(lgv.x*(y0-mu)*inv + lbv.x);
    float o1 = scrub(lgv.y*(y1-mu)*inv + lbv.y);
    h_out[(size_t)row*(EMBED/2) + lane] = pack2(o0, o1);
  }
}

// ---------------------------------------------------------------------------
// g[gdst][:] = sum over bucketed srcs of h[b*SEQ+src][:]. One wave per dst row.
// (round-0 exact)
__global__ __launch_bounds__(256) void k_gather(
    const int* __restrict__ cnt, const unsigned short* __restrict__ bucket,
    const int* __restrict__ ovf_cnt, const int* __restrict__ ovf,
    const unsigned int* __restrict__ h, unsigned int* __restrict__ g){
  int wv = threadIdx.x >> 6, lane = threadIdx.x & 63;
  int gdst = blockIdx.x*4 + wv;
  int n = cnt[gdst]; n = n > BCAP ? BCAP : n;
  int b = gdst >> 11;
  const unsigned int* hb = h + (size_t)b*SEQ*(EMBED/2);
  const unsigned short* bk = bucket + (size_t)gdst*BCAP;
  float ax = 0.f, ay = 0.f;
  for (int i = 0; i < n; ++i){
    unsigned int v = hb[(size_t)bk[i]*(EMBED/2) + lane];
    ax += lo2f(v); ay += hi2f(v);
  }
  int on = *ovf_cnt; on = on > OVCAP ? OVCAP : on;   // ~always 0
  for (int idx = 0; idx < on; ++idx){
    int pk = ovf[idx];
    if (((pk >> 16) & 0x7fff) == gdst){
      unsigned int v = h[(size_t)(pk & 0xffff)*(EMBED/2) + lane];
      ax += lo2f(v); ay += hi2f(v);
    }
  }
  g[(size_t)gdst*(EMBED/2) + lane] = pack2(scrub(ax), scrub(ay));
}

// ---------------------------------------------------------------------------
// MFMA upd+relu+pool, barrier-free. j-SPLIT for latency hiding:
//   round-0 had 512 blocks (2/CU, 8 waves/CU) — all pipes idle, latency-bound
//   on the per-wave 128KB Wcs sweep. Split the 16 j-tiles into 2 halves:
//   grid 1024 (4/CU, 16 waves/CU), acc[16]->acc[8], same MFMA/atomic totals.
//   Block pairs (2k,2k+1) share the same h/g rows -> L2-local.
__global__ __launch_bounds__(256) void k_upd_mfma(
    const short* __restrict__ h, const short* __restrict__ g,
    const short* __restrict__ Wcs, const float* __restrict__ Wupd_b,
    float* __restrict__ pool){
  int tid = threadIdx.x;
  int wave = (blockIdx.x >> 1)*4 + (tid >> 6); // row-group 0..2047
  int half = blockIdx.x & 1;                   // which 8 j-tiles
  int lane = tid & 63;
  int row0 = wave * 16;
  int b = row0 >> 11;                      // / SEQ
  int m = lane & 15, lg = lane >> 4;
  const short* hrow = h + (size_t)(row0+m)*EMBED + lg*8;
  const short* grow = g + (size_t)(row0+m)*EMBED + lg*8;

  f32x4 acc[8];
  #pragma unroll
  for (int j = 0; j < 8; ++j) acc[j] = (f32x4){0.f,0.f,0.f,0.f};

  const s16x8* Bp = (const s16x8*)Wcs;
  #pragma unroll
  for (int c = 0; c < 8; ++c){
    s16x8 a = (c < 4) ? *(const s16x8*)(hrow + c*32)
                      : *(const s16x8*)(grow + (c-4)*32);
    #pragma unroll
    for (int j = 0; j < 8; ++j){
      s16x8 bfr = Bp[(c*16 + half*8 + j)*64 + lane];
      acc[j] = __builtin_amdgcn_mfma_f32_16x16x32_bf16(a, bfr, acc[j], 0, 0, 0);
    }
  }

  // C/D layout: col = lane&15, row = (lane>>4)*4 + reg
  #pragma unroll
  for (int j = 0; j < 8; ++j){
    int n = (half*8 + j)*16 + (lane & 15);
    float bias = Wupd_b[n];
    float v = 0.f;
    #pragma unroll
    for (int r = 0; r < 4; ++r) v += fmaxf(acc[j][r] + bias, 0.f);
    v += __shfl_down(v, 32);
    v += __shfl_down(v, 16);
    if (lane < 16) atomicAdd(&pool[b*HID + n], scrub(v));
  }
}

// ---------------------------------------------------------------------------
__global__ void k_cls(const float* __restrict__ pool, const float* __restrict__ cls_w,
                      const float* __restrict__ cls_b, float* __restrict__ out){
  int tid = threadIdx.x;
  if (tid >= B_SZ*NCLS) return;
  int b = tid / NCLS, c = tid - b*NCLS;
  const float* p = pool + b*HID;
  const float* w = cls_w + c*HID;
  float s = 0.f;
  for (int h1 = 0; h1 < HID; ++h1) s += p[h1]*w[h1];
  out[tid] = scrub(s * (1.0f/SEQ) + cls_b[c]);
}

// ---------------------------------------------------------------------------
extern "C" void kernel_launch(void* const* d_in, const int* in_sizes, int n_in,
                              void* d_out, int out_size, void* d_ws, size_t ws_size,
                              hipStream_t stream) {
  const int*   tokens = (const int*)d_in[0];
  const int*   edges  = (const int*)d_in[2];
  const float* emb    = (const float*)d_in[3];
  const float* A_log  = (const float*)d_in[4];
  const float* B_w    = (const float*)d_in[5];
  const float* C_w    = (const float*)d_in[6];
  const float* D_skip = (const float*)d_in[7];
  const float* ln_g   = (const float*)d_in[8];
  const float* ln_b   = (const float*)d_in[9];
  const float* Wmsg   = (const float*)d_in[10];
  const float* Wupd   = (const float*)d_in[11];
  const float* Wupd_b = (const float*)d_in[12];
  const float* cls_w  = (const float*)d_in[13];
  const float* cls_b  = (const float*)d_in[14];
  float* out = (float*)d_out;

  // workspace layout (~26.5 MB) — round-0 exact
  char* ws = (char*)d_ws;
  float* c_tab = (float*)ws;  ws += 16*1024;                 // 4 KB used
  float* MT    = (float*)ws;  ws += (size_t)HID*EMBED*4;     // 128 KB
  short* Wcs   = (short*)ws;  ws += (size_t)HID*HID*2;       // 128 KB
  short* Bf    = (short*)ws;  ws += 16*1024;                 // 4 KB used
  char*  zbase = ws;
  float* pool  = (float*)ws;  ws += (size_t)B_SZ*HID*4;      // 16 KB
  int*   cnt   = (int*)ws;    ws += (size_t)NROW*4;          // 128 KB
  int*   ovf_cnt = (int*)ws;  ws += 64;
  int*   ovf   = (int*)ws;    ws += OVCAP*4;                 // 4 KB
  size_t zlen = (size_t)((char*)ws - zbase);
  unsigned short* bucket = (unsigned short*)ws; ws += (size_t)NROW*BCAP*2; // 2 MB
  short* x_bf  = (short*)ws;  ws += (size_t)NROW*EMBED*2;    // 8 MB
  short* h_bf  = (short*)ws;  ws += (size_t)NROW*EMBED*2;    // 8 MB
  short* g_bf  = (short*)ws;  ws += (size_t)NROW*EMBED*2;    // 8 MB

  hipMemsetAsync(zbase, 0, zlen, stream);
  hipLaunchKernelGGL(k_prep, dim3(PB_TOTAL), dim3(256), 0, stream,
                     tokens, emb, A_log, B_w, Wmsg, Wupd, edges,
                     c_tab, Bf, MT, (unsigned int*)x_bf, cnt, bucket, ovf_cnt, ovf);
  hipLaunchKernelGGL(k_ssm_fused, dim3(544), dim3(256), 0, stream,
                     x_bf, c_tab, C_w, D_skip, ln_g, ln_b, Bf, Wupd, MT,
                     (unsigned int*)h_bf, Wcs);
  hipLaunchKernelGGL(k_gather, dim3(NROW/4), dim3(256), 0, stream,
                     cnt, bucket, ovf_cnt, ovf, (const unsigned int*)h_bf,
                     (unsigned int*)g_bf);
  hipLaunchKernelGGL(k_upd_mfma, dim3(NROW/32), dim3(256), 0, stream,
                     h_bf, g_bf, Wcs, Wupd_b, pool);
  hipLaunchKernelGGL(k_cls, dim3(1), dim3(256), 0, stream, pool, cls_w, cls_b, out);
}